// Round 1
// baseline (656.756 us; speedup 1.0000x reference)
//
#include <hip/hip_runtime.h>
#include <hip/hip_bf16.h>
#include <math.h>

#define INPUT 2048
#define HIDDEN 128
#define BATCH 64
#define TSTEPS 512

// ---------------------------------------------------------------------------
// Kernel 1: xw[b,t,h] = dot(x[b,t,:], W_ih[h,:]) + b_ih[h] + b_hh[h]
// M = B*T = 32768 rows, K = 2048, N = 128. f32 everywhere.
// Tiling: BM=64 rows, BN=128 (all), BK=32. 256 threads, 8x4 acc per thread.
// LDS tiles stored k-major so inner-loop reads are contiguous float4.
// ---------------------------------------------------------------------------
#define BM 64
#define BK 32

__global__ __launch_bounds__(256) void gemm_xw_kernel(
    const float* __restrict__ x, const float* __restrict__ W,
    const float* __restrict__ b_ih, const float* __restrict__ b_hh,
    float* __restrict__ xw) {
  __shared__ float xs[BK][BM];     // [k][row]
  __shared__ float ws[BK][HIDDEN]; // [k][col]

  const int tid = threadIdx.x;
  const int block_row = blockIdx.x * BM;
  const int tc = tid & 31;   // col group: 32 groups of 4 cols
  const int tr = tid >> 5;   // row group: 8 groups of 8 rows

  float acc[8][4];
#pragma unroll
  for (int i = 0; i < 8; ++i)
#pragma unroll
    for (int j = 0; j < 4; ++j) acc[i][j] = 0.f;

  // staging indices
  const int xr = tid >> 2;            // row 0..63
  const int xkq = (tid & 3) * 8;      // k offset 0/8/16/24
  const int wh = tid >> 1;            // h 0..127
  const int wkq = (tid & 1) * 16;     // k offset 0/16

  for (int k0 = 0; k0 < INPUT; k0 += BK) {
    // ---- stage x tile: 64 rows x 32 k, 8 elems/thread (2x float4)
    {
      const float* src = x + (size_t)(block_row + xr) * INPUT + k0 + xkq;
      float4 v0 = ((const float4*)src)[0];
      float4 v1 = ((const float4*)src)[1];
      xs[xkq + 0][xr] = v0.x; xs[xkq + 1][xr] = v0.y;
      xs[xkq + 2][xr] = v0.z; xs[xkq + 3][xr] = v0.w;
      xs[xkq + 4][xr] = v1.x; xs[xkq + 5][xr] = v1.y;
      xs[xkq + 6][xr] = v1.z; xs[xkq + 7][xr] = v1.w;
    }
    // ---- stage W tile: 128 h x 32 k, 16 elems/thread (4x float4)
    {
      const float* src = W + (size_t)wh * INPUT + k0 + wkq;
      float4 v0 = ((const float4*)src)[0];
      float4 v1 = ((const float4*)src)[1];
      float4 v2 = ((const float4*)src)[2];
      float4 v3 = ((const float4*)src)[3];
      ws[wkq + 0][wh] = v0.x;  ws[wkq + 1][wh] = v0.y;
      ws[wkq + 2][wh] = v0.z;  ws[wkq + 3][wh] = v0.w;
      ws[wkq + 4][wh] = v1.x;  ws[wkq + 5][wh] = v1.y;
      ws[wkq + 6][wh] = v1.z;  ws[wkq + 7][wh] = v1.w;
      ws[wkq + 8][wh] = v2.x;  ws[wkq + 9][wh] = v2.y;
      ws[wkq + 10][wh] = v2.z; ws[wkq + 11][wh] = v2.w;
      ws[wkq + 12][wh] = v3.x; ws[wkq + 13][wh] = v3.y;
      ws[wkq + 14][wh] = v3.z; ws[wkq + 15][wh] = v3.w;
    }
    __syncthreads();

#pragma unroll
    for (int kk = 0; kk < BK; ++kk) {
      const float4 xa = *(const float4*)&xs[kk][tr * 8];
      const float4 xb = *(const float4*)&xs[kk][tr * 8 + 4];
      const float4 wv = *(const float4*)&ws[kk][tc * 4];
      const float xrv[8] = {xa.x, xa.y, xa.z, xa.w, xb.x, xb.y, xb.z, xb.w};
      const float wcv[4] = {wv.x, wv.y, wv.z, wv.w};
#pragma unroll
      for (int i = 0; i < 8; ++i)
#pragma unroll
        for (int j = 0; j < 4; ++j) acc[i][j] += xrv[i] * wcv[j];
    }
    __syncthreads();
  }

  // epilogue: add biases, store
  const int c0 = tc * 4;
  const float4 bi = *(const float4*)&b_ih[c0];
  const float4 bh = *(const float4*)&b_hh[c0];
  const float bias[4] = {bi.x + bh.x, bi.y + bh.y, bi.z + bh.z, bi.w + bh.w};
#pragma unroll
  for (int i = 0; i < 8; ++i) {
    const int row = block_row + tr * 8 + i;
    float4 o;
    o.x = acc[i][0] + bias[0];
    o.y = acc[i][1] + bias[1];
    o.z = acc[i][2] + bias[2];
    o.w = acc[i][3] + bias[3];
    *(float4*)&xw[(size_t)row * HIDDEN + c0] = o;
  }
}

// ---------------------------------------------------------------------------
// Kernel 2: sequential recurrence per batch row + fused FC epilogue.
// Grid: 64 blocks (one per batch row), 128 threads (thread h owns output h).
// W_hh row h lives in 32 float4 VGPRs; h-vector in LDS (broadcast reads).
// h_new[h] = tanh(xw[b,t,h] + sum_k hbuf[k] * W_hh[h][k])
// ---------------------------------------------------------------------------
__global__ __launch_bounds__(128) void rnn_rec_kernel(
    const float* __restrict__ xw, const float* __restrict__ W_hh,
    const float* __restrict__ W_fc, const float* __restrict__ b_fc,
    float* __restrict__ out) {
  const int b = blockIdx.x;
  const int h = threadIdx.x;

  __shared__ float hbuf[HIDDEN];
  __shared__ float red[HIDDEN];

  // load this thread's W_hh row into registers (32 float4 = 128 VGPR)
  float4 w[32];
  const float4* wrow = (const float4*)(W_hh + (size_t)h * HIDDEN);
#pragma unroll
  for (int i = 0; i < 32; ++i) w[i] = wrow[i];

  hbuf[h] = 0.f;
  __syncthreads();

  const float* xrow = xw + ((size_t)b * TSTEPS) * HIDDEN + h;
  float xw_next = xrow[0];
  float hn = 0.f;

  for (int t = 0; t < TSTEPS; ++t) {
    const float cur = xw_next;
    if (t + 1 < TSTEPS) xw_next = xrow[(size_t)(t + 1) * HIDDEN];

    float a0 = 0.f, a1 = 0.f, a2 = 0.f, a3 = 0.f;
    const float4* h4 = (const float4*)hbuf;
#pragma unroll
    for (int i = 0; i < 32; i += 4) {
      const float4 h0v = h4[i + 0];
      const float4 h1v = h4[i + 1];
      const float4 h2v = h4[i + 2];
      const float4 h3v = h4[i + 3];
      a0 += h0v.x * w[i + 0].x + h0v.y * w[i + 0].y + h0v.z * w[i + 0].z + h0v.w * w[i + 0].w;
      a1 += h1v.x * w[i + 1].x + h1v.y * w[i + 1].y + h1v.z * w[i + 1].z + h1v.w * w[i + 1].w;
      a2 += h2v.x * w[i + 2].x + h2v.y * w[i + 2].y + h2v.z * w[i + 2].z + h2v.w * w[i + 2].w;
      a3 += h3v.x * w[i + 3].x + h3v.y * w[i + 3].y + h3v.z * w[i + 3].z + h3v.w * w[i + 3].w;
    }
    const float val = cur + ((a0 + a1) + (a2 + a3));
    hn = tanhf(val);

    __syncthreads();          // all reads of hbuf done
    hbuf[h] = hn;
    __syncthreads();          // new h visible
  }

  // fused FC: out[b] = sum_h hn[h] * W_fc[h] + b_fc
  red[h] = hn * W_fc[h];
  __syncthreads();
  if (h == 0) {
    float s = b_fc[0];
#pragma unroll 8
    for (int i = 0; i < HIDDEN; ++i) s += red[i];
    out[b] = s;
  }
}

extern "C" void kernel_launch(void* const* d_in, const int* in_sizes, int n_in,
                              void* d_out, int out_size, void* d_ws, size_t ws_size,
                              hipStream_t stream) {
  const float* x    = (const float*)d_in[0];
  const float* W_ih = (const float*)d_in[1];
  const float* W_hh = (const float*)d_in[2];
  const float* b_ih = (const float*)d_in[3];
  const float* b_hh = (const float*)d_in[4];
  const float* W_fc = (const float*)d_in[5];
  const float* b_fc = (const float*)d_in[6];

  float* xw = (float*)d_ws;  // 32768 x 128 f32 = 16 MB scratch

  const int M = BATCH * TSTEPS;  // 32768
  gemm_xw_kernel<<<M / BM, 256, 0, stream>>>(x, W_ih, b_ih, b_hh, xw);
  rnn_rec_kernel<<<BATCH, 128, 0, stream>>>(xw, W_hh, W_fc, b_fc, (float*)d_out);
}

// Round 2
// 570.377 us; speedup vs baseline: 1.1514x; 1.1514x over previous
//
#include <hip/hip_runtime.h>
#include <hip/hip_bf16.h>
#include <math.h>

#define INPUT 2048
#define HIDDEN 128
#define BATCH 64
#define TSTEPS 512

// ---------------------------------------------------------------------------
// Kernel 1: xw[b,t,h] = dot(x[b,t,:], W_ih[h,:]) + b_ih[h] + b_hh[h]
// M = 32768, K = 2048, N = 128. f32. BM=64, BK=32, 256 threads, 8x4 acc.
// Register-staged LDS double buffer: one barrier per K-tile, global loads
// for tile k+1 issued before compute on tile k.
// ---------------------------------------------------------------------------
#define BM 64
#define BK 32

__global__ __launch_bounds__(256) void gemm_xw_kernel(
    const float* __restrict__ x, const float* __restrict__ W,
    const float* __restrict__ b_ih, const float* __restrict__ b_hh,
    float* __restrict__ xw) {
  __shared__ float xs[2][BK][BM];     // [buf][k][row]  16 KB
  __shared__ float ws[2][BK][HIDDEN]; // [buf][k][col]  32 KB

  const int tid = threadIdx.x;
  const int block_row = blockIdx.x * BM;
  const int tc = tid & 31;   // col group: 32 groups of 4 cols
  const int tr = tid >> 5;   // row group: 8 groups of 8 rows

  float acc[8][4];
#pragma unroll
  for (int i = 0; i < 8; ++i)
#pragma unroll
    for (int j = 0; j < 4; ++j) acc[i][j] = 0.f;

  // staging indices
  const int xr = tid >> 2;            // row 0..63
  const int xkq = (tid & 3) * 8;      // k offset 0/8/16/24
  const int wh = tid >> 1;            // h 0..127
  const int wkq = (tid & 1) * 16;     // k offset 0/16

  const float* xsrc_base = x + (size_t)(block_row + xr) * INPUT + xkq;
  const float* wsrc_base = W + (size_t)wh * INPUT + wkq;

  float4 xv0, xv1, wv0, wv1, wv2, wv3;

  // load tile 0 into regs
  {
    const float* s = xsrc_base;
    xv0 = ((const float4*)s)[0]; xv1 = ((const float4*)s)[1];
    const float* w = wsrc_base;
    wv0 = ((const float4*)w)[0]; wv1 = ((const float4*)w)[1];
    wv2 = ((const float4*)w)[2]; wv3 = ((const float4*)w)[3];
  }
  // write tile 0 to buf 0
  {
    xs[0][xkq + 0][xr] = xv0.x; xs[0][xkq + 1][xr] = xv0.y;
    xs[0][xkq + 2][xr] = xv0.z; xs[0][xkq + 3][xr] = xv0.w;
    xs[0][xkq + 4][xr] = xv1.x; xs[0][xkq + 5][xr] = xv1.y;
    xs[0][xkq + 6][xr] = xv1.z; xs[0][xkq + 7][xr] = xv1.w;
    ws[0][wkq + 0][wh] = wv0.x;  ws[0][wkq + 1][wh] = wv0.y;
    ws[0][wkq + 2][wh] = wv0.z;  ws[0][wkq + 3][wh] = wv0.w;
    ws[0][wkq + 4][wh] = wv1.x;  ws[0][wkq + 5][wh] = wv1.y;
    ws[0][wkq + 6][wh] = wv1.z;  ws[0][wkq + 7][wh] = wv1.w;
    ws[0][wkq + 8][wh] = wv2.x;  ws[0][wkq + 9][wh] = wv2.y;
    ws[0][wkq + 10][wh] = wv2.z; ws[0][wkq + 11][wh] = wv2.w;
    ws[0][wkq + 12][wh] = wv3.x; ws[0][wkq + 13][wh] = wv3.y;
    ws[0][wkq + 14][wh] = wv3.z; ws[0][wkq + 15][wh] = wv3.w;
  }
  __syncthreads();

  const int NT = INPUT / BK;  // 64
  for (int kt = 0; kt < NT; ++kt) {
    const int p = kt & 1;
    // issue global loads for next tile (latency hides under compute below)
    if (kt + 1 < NT) {
      const float* s = xsrc_base + (kt + 1) * BK;
      xv0 = ((const float4*)s)[0]; xv1 = ((const float4*)s)[1];
      const float* w = wsrc_base + (kt + 1) * BK;
      wv0 = ((const float4*)w)[0]; wv1 = ((const float4*)w)[1];
      wv2 = ((const float4*)w)[2]; wv3 = ((const float4*)w)[3];
    }

    // compute on buf p
#pragma unroll
    for (int kk = 0; kk < BK; ++kk) {
      const float4 xa = *(const float4*)&xs[p][kk][tr * 8];
      const float4 xb = *(const float4*)&xs[p][kk][tr * 8 + 4];
      const float4 wv = *(const float4*)&ws[p][kk][tc * 4];
      const float xrv[8] = {xa.x, xa.y, xa.z, xa.w, xb.x, xb.y, xb.z, xb.w};
      const float wcv[4] = {wv.x, wv.y, wv.z, wv.w};
#pragma unroll
      for (int i = 0; i < 8; ++i)
#pragma unroll
        for (int j = 0; j < 4; ++j) acc[i][j] += xrv[i] * wcv[j];
    }

    if (kt + 1 < NT) {
      const int q = p ^ 1;
      xs[q][xkq + 0][xr] = xv0.x; xs[q][xkq + 1][xr] = xv0.y;
      xs[q][xkq + 2][xr] = xv0.z; xs[q][xkq + 3][xr] = xv0.w;
      xs[q][xkq + 4][xr] = xv1.x; xs[q][xkq + 5][xr] = xv1.y;
      xs[q][xkq + 6][xr] = xv1.z; xs[q][xkq + 7][xr] = xv1.w;
      ws[q][wkq + 0][wh] = wv0.x;  ws[q][wkq + 1][wh] = wv0.y;
      ws[q][wkq + 2][wh] = wv0.z;  ws[q][wkq + 3][wh] = wv0.w;
      ws[q][wkq + 4][wh] = wv1.x;  ws[q][wkq + 5][wh] = wv1.y;
      ws[q][wkq + 6][wh] = wv1.z;  ws[q][wkq + 7][wh] = wv1.w;
      ws[q][wkq + 8][wh] = wv2.x;  ws[q][wkq + 9][wh] = wv2.y;
      ws[q][wkq + 10][wh] = wv2.z; ws[q][wkq + 11][wh] = wv2.w;
      ws[q][wkq + 12][wh] = wv3.x; ws[q][wkq + 13][wh] = wv3.y;
      ws[q][wkq + 14][wh] = wv3.z; ws[q][wkq + 15][wh] = wv3.w;
      __syncthreads();
    }
  }

  // epilogue: add biases, store
  const int c0 = tc * 4;
  const float4 bi = *(const float4*)&b_ih[c0];
  const float4 bh = *(const float4*)&b_hh[c0];
  const float bias[4] = {bi.x + bh.x, bi.y + bh.y, bi.z + bh.z, bi.w + bh.w};
#pragma unroll
  for (int i = 0; i < 8; ++i) {
    const int row = block_row + tr * 8 + i;
    float4 o;
    o.x = acc[i][0] + bias[0];
    o.y = acc[i][1] + bias[1];
    o.z = acc[i][2] + bias[2];
    o.w = acc[i][3] + bias[3];
    *(float4*)&xw[(size_t)row * HIDDEN + c0] = o;
  }
}

// ---------------------------------------------------------------------------
// Kernel 2: sequential recurrence per batch row + fused FC epilogue.
// Grid: 64 blocks, 256 threads. Thread pair (2h, 2h+1) computes output h:
// each owns half of W_hh[h][:], shfl_xor(1) combines. Double-buffered h
// vector in LDS -> ONE barrier per step. Fast tanh via __expf + rcp.
// Depth-2 global prefetch of xw.
// ---------------------------------------------------------------------------
__device__ __forceinline__ float fast_tanh(float x) {
  x = fminf(fmaxf(x, -15.f), 15.f);
  const float e = __expf(2.f * x);
  return (e - 1.f) * __builtin_amdgcn_rcpf(e + 1.f);
}

__global__ __launch_bounds__(256) void rnn_rec_kernel(
    const float* __restrict__ xw, const float* __restrict__ W_hh,
    const float* __restrict__ W_fc, const float* __restrict__ b_fc,
    float* __restrict__ out) {
  const int b = blockIdx.x;
  const int tid = threadIdx.x;
  const int h = tid >> 1;     // 0..127
  const int half = tid & 1;   // which 64-wide k-chunk

  __shared__ float hbuf[2][HIDDEN];

  // this thread's half-row of W_hh: 16 float4 = 64 VGPRs
  float4 w[16];
  const float4* wrow = (const float4*)(W_hh + (size_t)h * HIDDEN + half * 64);
#pragma unroll
  for (int i = 0; i < 16; ++i) w[i] = wrow[i];

  if (half == 0) hbuf[0][h] = 0.f;
  __syncthreads();

  const float* xrow = xw + ((size_t)b * TSTEPS) * HIDDEN + h;
  float xw0 = xrow[0];
  float xw1 = xrow[HIDDEN];
  float hlast = 0.f;

  for (int t = 0; t < TSTEPS; ++t) {
    const float cur = xw0;
    xw0 = xw1;
    if (t + 2 < TSTEPS) xw1 = xrow[(size_t)(t + 2) * HIDDEN];

    const float4* h4 = (const float4*)&hbuf[t & 1][half * 64];
    float a0 = 0.f, a1 = 0.f, a2 = 0.f, a3 = 0.f;
#pragma unroll
    for (int i = 0; i < 16; i += 4) {
      const float4 h0v = h4[i + 0];
      const float4 h1v = h4[i + 1];
      const float4 h2v = h4[i + 2];
      const float4 h3v = h4[i + 3];
      a0 += h0v.x * w[i + 0].x + h0v.y * w[i + 0].y + h0v.z * w[i + 0].z + h0v.w * w[i + 0].w;
      a1 += h1v.x * w[i + 1].x + h1v.y * w[i + 1].y + h1v.z * w[i + 1].z + h1v.w * w[i + 1].w;
      a2 += h2v.x * w[i + 2].x + h2v.y * w[i + 2].y + h2v.z * w[i + 2].z + h2v.w * w[i + 2].w;
      a3 += h3v.x * w[i + 3].x + h3v.y * w[i + 3].y + h3v.z * w[i + 3].z + h3v.w * w[i + 3].w;
    }
    float s = (a0 + a1) + (a2 + a3);
    s += __shfl_xor(s, 1);  // combine the two halves (adjacent lanes)

    hlast = fast_tanh(cur + s);
    if (half == 0) hbuf[(t + 1) & 1][h] = hlast;
    __syncthreads();
  }

  // fused FC: out[b] = sum_h hlast[h] * W_fc[h] + b_fc
  if (half == 0) hbuf[1][h] = hlast * W_fc[h];
  __syncthreads();
  if (tid < 64) {
    float s = hbuf[1][tid] + hbuf[1][tid + 64];
#pragma unroll
    for (int o = 32; o > 0; o >>= 1) s += __shfl_xor(s, o);
    if (tid == 0) out[b] = s + b_fc[0];
  }
}

extern "C" void kernel_launch(void* const* d_in, const int* in_sizes, int n_in,
                              void* d_out, int out_size, void* d_ws, size_t ws_size,
                              hipStream_t stream) {
  const float* x    = (const float*)d_in[0];
  const float* W_ih = (const float*)d_in[1];
  const float* W_hh = (const float*)d_in[2];
  const float* b_ih = (const float*)d_in[3];
  const float* b_hh = (const float*)d_in[4];
  const float* W_fc = (const float*)d_in[5];
  const float* b_fc = (const float*)d_in[6];

  float* xw = (float*)d_ws;  // 32768 x 128 f32 = 16 MB scratch

  const int M = BATCH * TSTEPS;  // 32768
  gemm_xw_kernel<<<M / BM, 256, 0, stream>>>(x, W_ih, b_ih, b_hh, xw);
  rnn_rec_kernel<<<BATCH, 256, 0, stream>>>(xw, W_hh, W_fc, b_fc, (float*)d_out);
}

// Round 3
// 465.787 us; speedup vs baseline: 1.4100x; 1.2245x over previous
//
#include <hip/hip_runtime.h>
#include <hip/hip_bf16.h>
#include <math.h>

#define INPUT 2048
#define HIDDEN 128
#define BATCH 64
#define TSTEPS 512

typedef __attribute__((ext_vector_type(8))) short bf16x8;
typedef __attribute__((ext_vector_type(4))) float f32x4;
typedef _Float16 half_t;
typedef __attribute__((ext_vector_type(2))) _Float16 half2_t;

__device__ __forceinline__ unsigned short f2bf(float f) {
  unsigned int u = __float_as_uint(f);
  unsigned int r = (u + 0x7fffu + ((u >> 16) & 1u)) >> 16;
  return (unsigned short)r;
}
__device__ __forceinline__ float bf2f(unsigned short h) {
  return __uint_as_float(((unsigned int)h) << 16);
}
__device__ __forceinline__ bf16x8 as_bf16x8(uint4 v) {
  return __builtin_bit_cast(bf16x8, v);
}

#if __has_builtin(__builtin_amdgcn_fdot2)
#define FDOT2(a, b, c) __builtin_amdgcn_fdot2((a), (b), (c), false)
#else
#define FDOT2(a, b, c) ((c) + (float)(a).x * (float)(b).x + (float)(a).y * (float)(b).y)
#endif

// ---------------------------------------------------------------------------
// Prep: W_ih f32 -> bf16 hi/lo pair; W_hh f32 -> packed f16 (half2 in uint).
// ---------------------------------------------------------------------------
__global__ __launch_bounds__(256) void prep_kernel(
    const float* __restrict__ W_ih, const float* __restrict__ W_hh,
    unsigned short* __restrict__ Wh, unsigned short* __restrict__ Wl,
    unsigned int* __restrict__ Whh2) {
  const int id = blockIdx.x * 256 + threadIdx.x;  // 65536 threads
  // W_ih: 128*2048 = 262144 f32 -> 4 per thread
  float4 v = ((const float4*)W_ih)[id];
  float vv[4] = {v.x, v.y, v.z, v.w};
  unsigned short h[4], l[4];
#pragma unroll
  for (int j = 0; j < 4; ++j) {
    h[j] = f2bf(vv[j]);
    float r = vv[j] - bf2f(h[j]);
    l[j] = f2bf(r);
  }
  ushort4 hv = {h[0], h[1], h[2], h[3]};
  ushort4 lv = {l[0], l[1], l[2], l[3]};
  ((ushort4*)Wh)[id] = hv;
  ((ushort4*)Wl)[id] = lv;
  // W_hh: 128*128 = 16384 f32 -> 8192 packed half2
  if (id < 8192) {
    float2 p = ((const float2*)W_hh)[id];
    half_t a = (half_t)p.x, b = (half_t)p.y;
    unsigned int u = (unsigned int)__builtin_bit_cast(unsigned short, a) |
                     ((unsigned int)__builtin_bit_cast(unsigned short, b) << 16);
    Whh2[id] = u;
  }
}

// ---------------------------------------------------------------------------
// GEMM: xw[row][h] = x[row]·W_ih[h] + b_ih[h] + b_hh[h], stored f16.
// MFMA 16x16x32 bf16 with hi/lo split (3 terms -> ~f32 accuracy).
// 512 thr = 8 waves (4 row-groups x 2 col-groups), BM=128, BK=32.
// LDS layout [term][kc][idx] of 16B granules: frag ds_read_b128 is
// 256B-contiguous per 16-lane phase -> conflict-free. 1 barrier/tile.
// ---------------------------------------------------------------------------
#define GBM 128
#define GBK 32
#define NKT (INPUT / GBK)  // 64

__global__ __launch_bounds__(512) void gemm_xw_mfma(
    const float* __restrict__ x, const unsigned short* __restrict__ Wh,
    const unsigned short* __restrict__ Wl, const float* __restrict__ b_ih,
    const float* __restrict__ b_hh, half_t* __restrict__ xw) {
  __shared__ uint4 sA[2][2][4][128];  // [buf][hi/lo][kc][m] : 32 KB
  __shared__ uint4 sB[2][2][4][128];  // [buf][hi/lo][kc][n] : 32 KB

  const int tid = threadIdx.x;
  const int lane = tid & 63;
  const int w = tid >> 6;       // 0..7
  const int wr = w >> 1;        // 0..3 row-group (32 rows each)
  const int wc = w & 1;         // 0..1 col-group (64 cols each)
  const int block_row = blockIdx.x * GBM;

  const int kcl = lane >> 4;          // 0..3
  const int l15 = lane & 15;
  const int arow = wr * 32 + l15;     // + rt*16
  const int bcol = wc * 64 + l15;     // + ct*16

  // staging assignment: thread -> (sm, skc)
  const int sm = tid & 127;
  const int skc = tid >> 7;  // 0..3
  const float* xsrc = x + (size_t)(block_row + sm) * INPUT + skc * 8;
  const unsigned short* whsrc = Wh + (size_t)sm * INPUT + skc * 8;
  const unsigned short* wlsrc = Wl + (size_t)sm * INPUT + skc * 8;

  f32x4 acc[2][4];
#pragma unroll
  for (int rt = 0; rt < 2; ++rt)
#pragma unroll
    for (int ct = 0; ct < 4; ++ct) acc[rt][ct] = (f32x4)0.f;

  // bias per (ct) for this lane's column
  float bias_c[4];
#pragma unroll
  for (int ct = 0; ct < 4; ++ct) {
    const int col = wc * 64 + ct * 16 + l15;
    bias_c[ct] = b_ih[col] + b_hh[col];
  }

  float4 av0, av1;
  uint4 bh4, bl4;

  auto LOADT = [&](int kt) {
    const int k0 = kt * GBK;
    av0 = ((const float4*)(xsrc + k0))[0];
    av1 = ((const float4*)(xsrc + k0))[1];
    bh4 = *(const uint4*)(whsrc + k0);
    bl4 = *(const uint4*)(wlsrc + k0);
  };
  auto WRITET = [&](int bufw) {
    float v[8] = {av0.x, av0.y, av0.z, av0.w, av1.x, av1.y, av1.z, av1.w};
    unsigned int hp[4], lp[4];
#pragma unroll
    for (int j = 0; j < 4; ++j) {
      unsigned short h0 = f2bf(v[2 * j]), h1 = f2bf(v[2 * j + 1]);
      float r0 = v[2 * j] - bf2f(h0), r1 = v[2 * j + 1] - bf2f(h1);
      unsigned short l0 = f2bf(r0), l1 = f2bf(r1);
      hp[j] = (unsigned int)h0 | ((unsigned int)h1 << 16);
      lp[j] = (unsigned int)l0 | ((unsigned int)l1 << 16);
    }
    uint4 hv = {hp[0], hp[1], hp[2], hp[3]};
    uint4 lv = {lp[0], lp[1], lp[2], lp[3]};
    sA[bufw][0][skc][sm] = hv;
    sA[bufw][1][skc][sm] = lv;
    sB[bufw][0][skc][sm] = bh4;
    sB[bufw][1][skc][sm] = bl4;
  };

  // prologue: stage tile 0
  LOADT(0);
  WRITET(0);
  __syncthreads();

  for (int kt = 0; kt < NKT; ++kt) {
    const int buf = kt & 1;
    if (kt + 1 < NKT) LOADT(kt + 1);

    // compute on buf
    uint4 ah[2], al[2], bh[4], bl[4];
#pragma unroll
    for (int rt = 0; rt < 2; ++rt) {
      ah[rt] = sA[buf][0][kcl][arow + rt * 16];
      al[rt] = sA[buf][1][kcl][arow + rt * 16];
    }
#pragma unroll
    for (int ct = 0; ct < 4; ++ct) {
      bh[ct] = sB[buf][0][kcl][bcol + ct * 16];
      bl[ct] = sB[buf][1][kcl][bcol + ct * 16];
    }
#pragma unroll
    for (int rt = 0; rt < 2; ++rt)
#pragma unroll
      for (int ct = 0; ct < 4; ++ct) {
        acc[rt][ct] = __builtin_amdgcn_mfma_f32_16x16x32_bf16(
            as_bf16x8(ah[rt]), as_bf16x8(bh[ct]), acc[rt][ct], 0, 0, 0);
        acc[rt][ct] = __builtin_amdgcn_mfma_f32_16x16x32_bf16(
            as_bf16x8(ah[rt]), as_bf16x8(bl[ct]), acc[rt][ct], 0, 0, 0);
        acc[rt][ct] = __builtin_amdgcn_mfma_f32_16x16x32_bf16(
            as_bf16x8(al[rt]), as_bf16x8(bh[ct]), acc[rt][ct], 0, 0, 0);
      }

    if (kt + 1 < NKT) WRITET(buf ^ 1);
    __syncthreads();
  }

  // epilogue: C layout col = lane&15, row = (lane>>4)*4 + reg
  const int rbase = block_row + wr * 32 + (lane >> 4) * 4;
#pragma unroll
  for (int rt = 0; rt < 2; ++rt)
#pragma unroll
    for (int ct = 0; ct < 4; ++ct) {
      const int col = wc * 64 + ct * 16 + l15;
#pragma unroll
      for (int j = 0; j < 4; ++j) {
        const int row = rbase + rt * 16 + j;
        xw[(size_t)row * HIDDEN + col] = (half_t)(acc[rt][ct][j] + bias_c[ct]);
      }
    }
}

// ---------------------------------------------------------------------------
// Recurrence: 64 blocks x 1 wave. Lane l owns h = l and h = l+64.
// W_hh rows (f16 half2-packed) live in 128 VGPRs. h vector = 64 half2 in LDS
// (256 B): 16 ds_read_b128 per lane per step. 128 v_dot2 per lane per step.
// Single wave -> no s_barrier cost. Fused FC epilogue.
// ---------------------------------------------------------------------------
__device__ __forceinline__ float fast_tanh(float x) {
  x = fminf(fmaxf(x, -15.f), 15.f);
  const float e = __expf(2.f * x);
  return (e - 1.f) * __builtin_amdgcn_rcpf(e + 1.f);
}

__global__ __launch_bounds__(64, 1) void rnn_rec_f16(
    const half_t* __restrict__ xw, const unsigned int* __restrict__ Whh2,
    const float* __restrict__ W_fc, const float* __restrict__ b_fc,
    float* __restrict__ out) {
  const int b = blockIdx.x;
  const int l = threadIdx.x;

  __shared__ unsigned int h2buf[2][64];  // 64 half2 per buffer

  // load W_hh rows l and l+64 as half2 (64 + 64 regs)
  half2_t w0[64], w1[64];
  {
    const uint4* r0 = (const uint4*)(Whh2 + (size_t)l * 64);
    const uint4* r1 = (const uint4*)(Whh2 + (size_t)(l + 64) * 64);
#pragma unroll
    for (int i = 0; i < 16; ++i) {
      uint4 q0 = r0[i];
      uint4 q1 = r1[i];
      w0[4 * i + 0] = __builtin_bit_cast(half2_t, q0.x);
      w0[4 * i + 1] = __builtin_bit_cast(half2_t, q0.y);
      w0[4 * i + 2] = __builtin_bit_cast(half2_t, q0.z);
      w0[4 * i + 3] = __builtin_bit_cast(half2_t, q0.w);
      w1[4 * i + 0] = __builtin_bit_cast(half2_t, q1.x);
      w1[4 * i + 1] = __builtin_bit_cast(half2_t, q1.y);
      w1[4 * i + 2] = __builtin_bit_cast(half2_t, q1.z);
      w1[4 * i + 3] = __builtin_bit_cast(half2_t, q1.w);
    }
  }

  h2buf[0][l] = 0u;
  __syncthreads();

  const half_t* xrow = xw + (size_t)b * TSTEPS * HIDDEN + l;
  float c0 = (float)xrow[0], c1 = (float)xrow[64];
  float n0 = (float)xrow[128], n1 = (float)xrow[192];
  float hn0 = 0.f, hn1 = 0.f;

  for (int t = 0; t < TSTEPS; ++t) {
    const float cur0 = c0, cur1 = c1;
    c0 = n0; c1 = n1;
    if (t + 2 < TSTEPS) {
      n0 = (float)xrow[(size_t)(t + 2) * HIDDEN];
      n1 = (float)xrow[(size_t)(t + 2) * HIDDEN + 64];
    }

    // read full h vector (64 half2 = 256B) into regs
    uint4 hq[16];
    const uint4* hb = (const uint4*)h2buf[t & 1];
#pragma unroll
    for (int i = 0; i < 16; ++i) hq[i] = hb[i];

    float a0[4] = {0.f, 0.f, 0.f, 0.f};
    float a1[4] = {0.f, 0.f, 0.f, 0.f};
#pragma unroll
    for (int i = 0; i < 16; ++i) {
      half2_t h0 = __builtin_bit_cast(half2_t, hq[i].x);
      half2_t h1 = __builtin_bit_cast(half2_t, hq[i].y);
      half2_t h2 = __builtin_bit_cast(half2_t, hq[i].z);
      half2_t h3 = __builtin_bit_cast(half2_t, hq[i].w);
      a0[0] = FDOT2(h0, w0[4 * i + 0], a0[0]);
      a0[1] = FDOT2(h1, w0[4 * i + 1], a0[1]);
      a0[2] = FDOT2(h2, w0[4 * i + 2], a0[2]);
      a0[3] = FDOT2(h3, w0[4 * i + 3], a0[3]);
      a1[0] = FDOT2(h0, w1[4 * i + 0], a1[0]);
      a1[1] = FDOT2(h1, w1[4 * i + 1], a1[1]);
      a1[2] = FDOT2(h2, w1[4 * i + 2], a1[2]);
      a1[3] = FDOT2(h3, w1[4 * i + 3], a1[3]);
    }
    hn0 = fast_tanh(cur0 + ((a0[0] + a0[1]) + (a0[2] + a0[3])));
    hn1 = fast_tanh(cur1 + ((a1[0] + a1[1]) + (a1[2] + a1[3])));

    half_t* nb = (half_t*)h2buf[(t + 1) & 1];
    nb[l] = (half_t)hn0;
    nb[l + 64] = (half_t)hn1;
    __syncthreads();  // single wave: compiles to waitcnt, ~free
  }

  // fused FC
  float s = hn0 * W_fc[l] + hn1 * W_fc[l + 64];
#pragma unroll
  for (int o = 32; o > 0; o >>= 1) s += __shfl_xor(s, o);
  if (l == 0) out[b] = s + b_fc[0];
}

extern "C" void kernel_launch(void* const* d_in, const int* in_sizes, int n_in,
                              void* d_out, int out_size, void* d_ws, size_t ws_size,
                              hipStream_t stream) {
  const float* x    = (const float*)d_in[0];
  const float* W_ih = (const float*)d_in[1];
  const float* W_hh = (const float*)d_in[2];
  const float* b_ih = (const float*)d_in[3];
  const float* b_hh = (const float*)d_in[4];
  const float* W_fc = (const float*)d_in[5];
  const float* b_fc = (const float*)d_in[6];

  char* ws = (char*)d_ws;
  half_t*         xwf16 = (half_t*)(ws);                    // 8 MB
  unsigned short* Wh    = (unsigned short*)(ws + 8388608);  // 512 KB
  unsigned short* Wl    = (unsigned short*)(ws + 8912896);  // 512 KB
  unsigned int*   Whh2  = (unsigned int*)(ws + 9437184);    // 32 KB

  prep_kernel<<<256, 256, 0, stream>>>(W_ih, W_hh, Wh, Wl, Whh2);
  gemm_xw_mfma<<<(BATCH * TSTEPS) / GBM, 512, 0, stream>>>(x, Wh, Wl, b_ih, b_hh, xwf16);
  rnn_rec_f16<<<BATCH, 64, 0, stream>>>(xwf16, Whh2, W_fc, b_fc, (float*)d_out);
}

// Round 7
// 372.688 us; speedup vs baseline: 1.7622x; 1.2498x over previous
//
#include <hip/hip_runtime.h>
#include <hip/hip_bf16.h>
#include <math.h>

#define INPUT 2048
#define HIDDEN 128
#define BATCH 64
#define TSTEPS 512

typedef _Float16 half_t;
typedef __attribute__((ext_vector_type(2))) _Float16 half2_t;
typedef __attribute__((ext_vector_type(8))) _Float16 f16x8;
typedef __attribute__((ext_vector_type(4))) float f32x4;

static __device__ __forceinline__ f16x8 as_f16x8(uint4 v) {
  return __builtin_bit_cast(f16x8, v);
}
static __device__ __forceinline__ half2_t as_h2(unsigned int v) {
  return __builtin_bit_cast(half2_t, v);
}
static __device__ __forceinline__ unsigned int h2u(half2_t v) {
  return __builtin_bit_cast(unsigned int, v);
}
static __device__ __forceinline__ half2_t pkrtz(float a, float b) {
  return __builtin_bit_cast(half2_t, __builtin_amdgcn_cvt_pkrtz(a, b));
}

#if __has_builtin(__builtin_amdgcn_fdot2)
#define FDOT2(a, b, c) __builtin_amdgcn_fdot2((a), (b), (c), false)
#else
#define FDOT2(a, b, c) ((c) + (float)(a)[0] * (float)(b)[0] + (float)(a)[1] * (float)(b)[1])
#endif

// ---------------------------------------------------------------------------
// Prep: W_ih f32 -> f16 (RTE); W_hh f32 -> packed half2.
// ---------------------------------------------------------------------------
__global__ __launch_bounds__(256) void prep_kernel(
    const float* __restrict__ W_ih, const float* __restrict__ W_hh,
    unsigned short* __restrict__ Wih16, unsigned int* __restrict__ Whh2) {
  const int id = blockIdx.x * 256 + threadIdx.x;  // 65536 threads
  float4 v = ((const float4*)W_ih)[id];
  half_t h0 = (half_t)v.x, h1 = (half_t)v.y, h2 = (half_t)v.z, h3 = (half_t)v.w;
  ushort4 o = {__builtin_bit_cast(unsigned short, h0), __builtin_bit_cast(unsigned short, h1),
               __builtin_bit_cast(unsigned short, h2), __builtin_bit_cast(unsigned short, h3)};
  ((ushort4*)Wih16)[id] = o;
  if (id < 8192) {
    float2 p = ((const float2*)W_hh)[id];
    half_t a = (half_t)p.x, b = (half_t)p.y;
    Whh2[id] = (unsigned int)__builtin_bit_cast(unsigned short, a) |
               ((unsigned int)__builtin_bit_cast(unsigned short, b) << 16);
  }
}

// ---------------------------------------------------------------------------
// GEMM: xw[row][h] = x[row]·W_ih[h] + b_ih[h] + b_hh[h], stored f16.
// Single-term f16 MFMA 16x16x32. BM=64, BK=64, 256 thr (4 waves: 2 row-grp x
// 2 col-grp), grid 512 -> 2 blocks/CU for stall overlap. LDS granule layout
// [kc][idx] (granule = 8 f16 = 16 B): frag reads + staged writes are b128 at
// optimal 8-cycle wave throughput. 1 barrier/tile, reg-staged double buffer.
// ---------------------------------------------------------------------------
#define GBM 64
#define GBK 64
#define GNKT (INPUT / GBK)  // 32

__global__ __launch_bounds__(256) void gemm_xw_f16(
    const float* __restrict__ x, const unsigned short* __restrict__ Wih16,
    const float* __restrict__ b_ih, const float* __restrict__ b_hh,
    half_t* __restrict__ xw) {
  __shared__ uint4 sA[2][8][64];   // [buf][kc][m]  16 KB
  __shared__ uint4 sB[2][8][128];  // [buf][kc][n]  32 KB

  const int tid = threadIdx.x;
  const int lane = tid & 63;
  const int w = tid >> 6;
  const int wr = w >> 1, wc = w & 1;
  const int block_row = blockIdx.x * GBM;
  const int kcl = lane >> 4;
  const int l15 = lane & 15;

  // staging maps
  const int xm = tid & 63, xkq = tid >> 6;   // x: row, k-quarter (16 f32)
  const int wn = tid & 127, wkh = tid >> 7;  // W: col, k-half (32 f16)
  const float* xsrc = x + (size_t)(block_row + xm) * INPUT + xkq * 16;
  const unsigned short* wsrc = Wih16 + (size_t)wn * INPUT + wkh * 32;

  f32x4 acc[2][4];
#pragma unroll
  for (int rt = 0; rt < 2; ++rt)
#pragma unroll
    for (int ct = 0; ct < 4; ++ct) acc[rt][ct] = (f32x4)0.f;

  float bias_c[4];
#pragma unroll
  for (int ct = 0; ct < 4; ++ct) {
    const int col = wc * 64 + ct * 16 + l15;
    bias_c[ct] = b_ih[col] + b_hh[col];
  }

  float4 xv[4];
  uint4 wv[4];
  auto LOADT = [&](int kt) {
    const float4* xs = (const float4*)(xsrc + kt * GBK);
    xv[0] = xs[0]; xv[1] = xs[1]; xv[2] = xs[2]; xv[3] = xs[3];
    const uint4* ws4 = (const uint4*)(wsrc + kt * GBK);
    wv[0] = ws4[0]; wv[1] = ws4[1]; wv[2] = ws4[2]; wv[3] = ws4[3];
  };
  auto WRITET = [&](int bf) {
#pragma unroll
    for (int g = 0; g < 2; ++g) {
      half2_t p0 = pkrtz(xv[2 * g].x, xv[2 * g].y);
      half2_t p1 = pkrtz(xv[2 * g].z, xv[2 * g].w);
      half2_t p2 = pkrtz(xv[2 * g + 1].x, xv[2 * g + 1].y);
      half2_t p3 = pkrtz(xv[2 * g + 1].z, xv[2 * g + 1].w);
      uint4 q = {h2u(p0), h2u(p1), h2u(p2), h2u(p3)};
      sA[bf][xkq * 2 + g][xm] = q;
    }
#pragma unroll
    for (int g = 0; g < 4; ++g) sB[bf][wkh * 4 + g][wn] = wv[g];
  };

  LOADT(0);
  WRITET(0);
  __syncthreads();

  for (int kt = 0; kt < GNKT; ++kt) {
    const int p = kt & 1;
    if (kt + 1 < GNKT) LOADT(kt + 1);

    uint4 af[2][2], bfr[2][4];
#pragma unroll
    for (int kf = 0; kf < 2; ++kf) {
#pragma unroll
      for (int rt = 0; rt < 2; ++rt)
        af[kf][rt] = sA[p][kf * 4 + kcl][wr * 32 + rt * 16 + l15];
#pragma unroll
      for (int ct = 0; ct < 4; ++ct)
        bfr[kf][ct] = sB[p][kf * 4 + kcl][wc * 64 + ct * 16 + l15];
    }
#pragma unroll
    for (int kf = 0; kf < 2; ++kf)
#pragma unroll
      for (int rt = 0; rt < 2; ++rt)
#pragma unroll
        for (int ct = 0; ct < 4; ++ct)
          acc[rt][ct] = __builtin_amdgcn_mfma_f32_16x16x32_f16(
              as_f16x8(af[kf][rt]), as_f16x8(bfr[kf][ct]), acc[rt][ct], 0, 0, 0);

    if (kt + 1 < GNKT) WRITET(p ^ 1);
    __syncthreads();
  }

  // epilogue: C layout col = lane&15, row = (lane>>4)*4 + j  (verified R3)
  const int rbase = block_row + wr * 32 + (lane >> 4) * 4;
#pragma unroll
  for (int rt = 0; rt < 2; ++rt)
#pragma unroll
    for (int ct = 0; ct < 4; ++ct) {
      const int col = wc * 64 + ct * 16 + l15;
#pragma unroll
      for (int j = 0; j < 4; ++j) {
        const int row = rbase + rt * 16 + j;
        xw[(size_t)row * HIDDEN + col] = (half_t)(acc[rt][ct][j] + bias_c[ct]);
      }
    }
}

// ---------------------------------------------------------------------------
// Recurrence: 64 blocks x 256 threads (4 waves across 4 SIMDs).
// Thread pair (2h, 2h+1) computes h: each owns a 64-k half of W_hh[h] as 32
// packed half2 in VGPRs; h vector = 64 half2 (256 B) double-buffered in LDS.
// Per thread/step: 8 ds_read_b128 (broadcast), 32 v_dot2, DPP xor-1 combine
// (VALU pipe, no LDS), redundant fast-tanh, 1 b16 write, ONE barrier.
// ---------------------------------------------------------------------------
__device__ __forceinline__ float fast_tanh(float x) {
  x = fminf(fmaxf(x, -15.f), 15.f);
  const float e = __expf(2.f * x);
  return (e - 1.f) * __builtin_amdgcn_rcpf(e + 1.f);
}

__global__ __launch_bounds__(256) void rnn_rec_dot2(
    const half_t* __restrict__ xw, const unsigned int* __restrict__ Whh2,
    const float* __restrict__ W_fc, const float* __restrict__ b_fc,
    float* __restrict__ out) {
  const int b = blockIdx.x;
  const int tid = threadIdx.x;
  const int h = tid >> 1;
  const int hf = tid & 1;

  __shared__ unsigned int h2buf[2][64];
  __shared__ float red[4];

  // this thread's 64-k half of W_hh[h] as 32 half2 (32 VGPRs)
  half2_t wreg[32];
  {
    const uint4* wr4 = (const uint4*)(Whh2 + (size_t)h * 64 + hf * 32);
#pragma unroll
    for (int i = 0; i < 8; ++i) {
      uint4 q = wr4[i];
      wreg[4 * i + 0] = as_h2(q.x);
      wreg[4 * i + 1] = as_h2(q.y);
      wreg[4 * i + 2] = as_h2(q.z);
      wreg[4 * i + 3] = as_h2(q.w);
    }
  }

  if (tid < 64) h2buf[0][tid] = 0u;
  __syncthreads();

  const half_t* xrow = xw + (size_t)b * TSTEPS * HIDDEN + h;
  float c = (float)xrow[0];
  float n = (float)xrow[HIDDEN];
  float hn = 0.f;

  for (int t = 0; t < TSTEPS; ++t) {
    const float cur = c;
    c = n;
    if (t + 2 < TSTEPS) n = (float)xrow[(size_t)(t + 2) * HIDDEN];

    const uint4* hb = (const uint4*)&h2buf[t & 1][hf * 32];
    uint4 hq[8];
#pragma unroll
    for (int i = 0; i < 8; ++i) hq[i] = hb[i];

    float a0 = 0.f, a1 = 0.f, a2 = 0.f, a3 = 0.f;
#pragma unroll
    for (int i = 0; i < 8; ++i) {
      a0 = FDOT2(as_h2(hq[i].x), wreg[4 * i + 0], a0);
      a1 = FDOT2(as_h2(hq[i].y), wreg[4 * i + 1], a1);
      a2 = FDOT2(as_h2(hq[i].z), wreg[4 * i + 2], a2);
      a3 = FDOT2(as_h2(hq[i].w), wreg[4 * i + 3], a3);
    }
    float s = (a0 + a1) + (a2 + a3);
    // combine pair halves: DPP quad_perm(1,0,3,2) = lane xor 1 (VALU pipe)
    float so = __builtin_bit_cast(
        float, __builtin_amdgcn_mov_dpp(__builtin_bit_cast(int, s), 0xB1, 0xF, 0xF, true));
    hn = fast_tanh(cur + s + so);

    if (hf == 0) ((half_t*)h2buf[(t + 1) & 1])[h] = (half_t)hn;
    __syncthreads();
  }

  // fused FC: out[b] = sum_h hn[h] * W_fc[h] + b_fc  (count each h once)
  float fcv = (hf == 0) ? hn * W_fc[h] : 0.f;
#pragma unroll
  for (int o = 32; o > 0; o >>= 1) fcv += __shfl_xor(fcv, o);
  if ((tid & 63) == 0) red[tid >> 6] = fcv;
  __syncthreads();
  if (tid == 0) out[b] = red[0] + red[1] + red[2] + red[3] + b_fc[0];
}

extern "C" void kernel_launch(void* const* d_in, const int* in_sizes, int n_in,
                              void* d_out, int out_size, void* d_ws, size_t ws_size,
                              hipStream_t stream) {
  const float* x    = (const float*)d_in[0];
  const float* W_ih = (const float*)d_in[1];
  const float* W_hh = (const float*)d_in[2];
  const float* b_ih = (const float*)d_in[3];
  const float* b_hh = (const float*)d_in[4];
  const float* W_fc = (const float*)d_in[5];
  const float* b_fc = (const float*)d_in[6];

  char* ws = (char*)d_ws;
  half_t*         xwf16 = (half_t*)ws;                                     // 8 MB
  unsigned short* Wih16 = (unsigned short*)(ws + (8u << 20));              // 512 KB
  unsigned int*   Whh2  = (unsigned int*)(ws + (8u << 20) + (512u << 10)); // 32 KB

  prep_kernel<<<256, 256, 0, stream>>>(W_ih, W_hh, Wih16, Whh2);
  gemm_xw_f16<<<(BATCH * TSTEPS) / GBM, 256, 0, stream>>>(x, Wih16, b_ih, b_hh, xwf16);
  rnn_rec_dot2<<<BATCH, 256, 0, stream>>>(xwf16, Whh2, W_fc, b_fc, (float*)d_out);
}

// Round 8
// 318.680 us; speedup vs baseline: 2.0609x; 1.1695x over previous
//
#include <hip/hip_runtime.h>
#include <hip/hip_bf16.h>
#include <math.h>

#define INPUT 2048
#define HIDDEN 128
#define BATCH 64
#define TSTEPS 512

typedef _Float16 half_t;
typedef __attribute__((ext_vector_type(2))) _Float16 half2_t;
typedef __attribute__((ext_vector_type(8))) _Float16 f16x8;
typedef __attribute__((ext_vector_type(4))) float f32x4;

static __device__ __forceinline__ f16x8 as_f16x8(uint4 v) {
  return __builtin_bit_cast(f16x8, v);
}
static __device__ __forceinline__ unsigned int h2u(half2_t v) {
  return __builtin_bit_cast(unsigned int, v);
}
static __device__ __forceinline__ half2_t pkrtz(float a, float b) {
  return __builtin_bit_cast(half2_t, __builtin_amdgcn_cvt_pkrtz(a, b));
}
static __device__ __forceinline__ float h2f(unsigned short u) {
  return (float)__builtin_bit_cast(half_t, u);
}

// tanh(x) = 1 - 2/(e^{2x}+1); e^{2x} = 2^{x*2/ln2}. 5 instrs, saturates
// correctly at +-inf (exp2->0 gives -1, exp2->inf gives +1).
static __device__ __forceinline__ float tanh_fast(float x) {
#if __has_builtin(__builtin_amdgcn_exp2f)
  const float e = __builtin_amdgcn_exp2f(x * 2.885390082f);
#else
  const float e = exp2f(x * 2.885390082f);
#endif
  return 1.f - 2.f * __builtin_amdgcn_rcpf(e + 1.f);
}

// ---------------------------------------------------------------------------
// Prep: W_ih f32 -> f16 (RTE); W_hh f32 -> packed half2 (k-major).
// ---------------------------------------------------------------------------
__global__ __launch_bounds__(256) void prep_kernel(
    const float* __restrict__ W_ih, const float* __restrict__ W_hh,
    unsigned short* __restrict__ Wih16, unsigned int* __restrict__ Whh2) {
  const int id = blockIdx.x * 256 + threadIdx.x;  // 65536 threads
  float4 v = ((const float4*)W_ih)[id];
  half_t h0 = (half_t)v.x, h1 = (half_t)v.y, h2 = (half_t)v.z, h3 = (half_t)v.w;
  ushort4 o = {__builtin_bit_cast(unsigned short, h0), __builtin_bit_cast(unsigned short, h1),
               __builtin_bit_cast(unsigned short, h2), __builtin_bit_cast(unsigned short, h3)};
  ((ushort4*)Wih16)[id] = o;
  if (id < 8192) {
    float2 p = ((const float2*)W_hh)[id];
    half_t a = (half_t)p.x, b = (half_t)p.y;
    Whh2[id] = (unsigned int)__builtin_bit_cast(unsigned short, a) |
               ((unsigned int)__builtin_bit_cast(unsigned short, b) << 16);
  }
}

// ---------------------------------------------------------------------------
// GEMM: xw[row][h] = x[row]·W_ih[h] + b_ih[h] + b_hh[h], stored f16.
// (unchanged from R7 — passed at ~absmax 3.9e-3)
// ---------------------------------------------------------------------------
#define GBM 64
#define GBK 64
#define GNKT (INPUT / GBK)  // 32

__global__ __launch_bounds__(256) void gemm_xw_f16(
    const float* __restrict__ x, const unsigned short* __restrict__ Wih16,
    const float* __restrict__ b_ih, const float* __restrict__ b_hh,
    half_t* __restrict__ xw) {
  __shared__ uint4 sA[2][8][64];   // [buf][kc][m]  16 KB
  __shared__ uint4 sB[2][8][128];  // [buf][kc][n]  32 KB

  const int tid = threadIdx.x;
  const int lane = tid & 63;
  const int w = tid >> 6;
  const int wr = w >> 1, wc = w & 1;
  const int block_row = blockIdx.x * GBM;
  const int kcl = lane >> 4;
  const int l15 = lane & 15;

  const int xm = tid & 63, xkq = tid >> 6;   // x: row, k-quarter (16 f32)
  const int wn = tid & 127, wkh = tid >> 7;  // W: col, k-half (32 f16)
  const float* xsrc = x + (size_t)(block_row + xm) * INPUT + xkq * 16;
  const unsigned short* wsrc = Wih16 + (size_t)wn * INPUT + wkh * 32;

  f32x4 acc[2][4];
#pragma unroll
  for (int rt = 0; rt < 2; ++rt)
#pragma unroll
    for (int ct = 0; ct < 4; ++ct) acc[rt][ct] = (f32x4)0.f;

  float bias_c[4];
#pragma unroll
  for (int ct = 0; ct < 4; ++ct) {
    const int col = wc * 64 + ct * 16 + l15;
    bias_c[ct] = b_ih[col] + b_hh[col];
  }

  float4 xv[4];
  uint4 wv[4];
  auto LOADT = [&](int kt) {
    const float4* xs = (const float4*)(xsrc + kt * GBK);
    xv[0] = xs[0]; xv[1] = xs[1]; xv[2] = xs[2]; xv[3] = xs[3];
    const uint4* ws4 = (const uint4*)(wsrc + kt * GBK);
    wv[0] = ws4[0]; wv[1] = ws4[1]; wv[2] = ws4[2]; wv[3] = ws4[3];
  };
  auto WRITET = [&](int bf) {
#pragma unroll
    for (int g = 0; g < 2; ++g) {
      half2_t p0 = pkrtz(xv[2 * g].x, xv[2 * g].y);
      half2_t p1 = pkrtz(xv[2 * g].z, xv[2 * g].w);
      half2_t p2 = pkrtz(xv[2 * g + 1].x, xv[2 * g + 1].y);
      half2_t p3 = pkrtz(xv[2 * g + 1].z, xv[2 * g + 1].w);
      uint4 q = {h2u(p0), h2u(p1), h2u(p2), h2u(p3)};
      sA[bf][xkq * 2 + g][xm] = q;
    }
#pragma unroll
    for (int g = 0; g < 4; ++g) sB[bf][wkh * 4 + g][wn] = wv[g];
  };

  LOADT(0);
  WRITET(0);
  __syncthreads();

  for (int kt = 0; kt < GNKT; ++kt) {
    const int p = kt & 1;
    if (kt + 1 < GNKT) LOADT(kt + 1);

    uint4 af[2][2], bfr[2][4];
#pragma unroll
    for (int kf = 0; kf < 2; ++kf) {
#pragma unroll
      for (int rt = 0; rt < 2; ++rt)
        af[kf][rt] = sA[p][kf * 4 + kcl][wr * 32 + rt * 16 + l15];
#pragma unroll
      for (int ct = 0; ct < 4; ++ct)
        bfr[kf][ct] = sB[p][kf * 4 + kcl][wc * 64 + ct * 16 + l15];
    }
#pragma unroll
    for (int kf = 0; kf < 2; ++kf)
#pragma unroll
      for (int rt = 0; rt < 2; ++rt)
#pragma unroll
        for (int ct = 0; ct < 4; ++ct)
          acc[rt][ct] = __builtin_amdgcn_mfma_f32_16x16x32_f16(
              as_f16x8(af[kf][rt]), as_f16x8(bfr[kf][ct]), acc[rt][ct], 0, 0, 0);

    if (kt + 1 < GNKT) WRITET(p ^ 1);
    __syncthreads();
  }

  const int rbase = block_row + wr * 32 + (lane >> 4) * 4;
#pragma unroll
  for (int rt = 0; rt < 2; ++rt)
#pragma unroll
    for (int ct = 0; ct < 4; ++ct) {
      const int col = wc * 64 + ct * 16 + l15;
#pragma unroll
      for (int j = 0; j < 4; ++j) {
        const int row = rbase + rt * 16 + j;
        xw[(size_t)row * HIDDEN + col] = (half_t)(acc[rt][ct][j] + bias_c[ct]);
      }
    }
}

// ---------------------------------------------------------------------------
// Recurrence via MFMA: 4 blocks x 16 batch rows, 256 threads (4 waves).
// D[h'][batch] = W_hh[h'][:] · h[:][batch] + xw  =>  A = W_hh (VGPR-resident,
// wave w owns h'-tiles {2w,2w+1}), B = h-state in LDS [batch][k] f16 with
// XOR swizzle ^((batch&7)<<4). C-input of the MFMA chain = xw (prefetched
// b64 f16, cvt to f32) — folds the add. D layout (col=batch,row=h') writes
// straight back as contiguous b64 into the [batch][k] state. tanh = 5 instr.
// One barrier per step; 2-step unroll keeps all reg arrays statically
// indexed and the LDS double-buffer parity compile-time.
// ---------------------------------------------------------------------------
#define RB 16

__global__ __launch_bounds__(256) void rnn_rec_mfma(
    const half_t* __restrict__ xw, const unsigned int* __restrict__ Whh2,
    const float* __restrict__ W_fc, const float* __restrict__ b_fc,
    float* __restrict__ out) {
  const int blk = blockIdx.x;    // 0..3
  const int tid = threadIdx.x;
  const int lane = tid & 63;
  const int w = tid >> 6;        // wave 0..3 -> h' tiles 2w, 2w+1
  const int bl = lane & 15;      // batch-local 0..15
  const int g = lane >> 4;       // k-group 0..3
  const int swz = (bl & 7) << 4; // LDS XOR swizzle (bits 4..6)

  __shared__ half_t st[2][RB][HIDDEN];  // 8 KB state double buffer
  __shared__ float red[256];

  // A-frags: W_hh rows. frag(mi,kt): W_hh[(2w+mi)*16+bl][kt*32+g*8 .. +7]
  uint4 afr[2][4];
#pragma unroll
  for (int mi = 0; mi < 2; ++mi)
#pragma unroll
    for (int kt = 0; kt < 4; ++kt)
      afr[mi][kt] = *(const uint4*)(Whh2 + ((size_t)((2 * w + mi) * 16 + bl)) * 64 +
                                    kt * 16 + g * 4);

  // zero state[0]
#pragma unroll
  for (int i = 0; i < 4; ++i) ((unsigned int*)st)[tid + 256 * i] = 0u;
  __syncthreads();

  // xw base pointers for this lane's two h'-tiles (b64 = 4 f16 per tile)
  const half_t* xb0 = xw + ((size_t)(blk * RB + bl) * TSTEPS) * HIDDEN + w * 32 + g * 4;
  const half_t* xb1 = xb0 + 16;

  float hh[2][4];  // last tanh outputs (persist for FC)

  auto STEP = [&](int t, const half_t* stR, half_t* stW, ushort4 xc0, ushort4 xc1) {
    // B-frags: full h-state, conflict-free via swizzle
    uint4 bfr[4];
#pragma unroll
    for (int kt = 0; kt < 4; ++kt) {
      const int off = (bl * 256 + kt * 64 + g * 16) ^ swz;
      bfr[kt] = *(const uint4*)((const char*)stR + off);
    }
    // C-input = xw (f16 -> f32)
    f32x4 a0, a1;
    a0[0] = h2f(xc0.x); a0[1] = h2f(xc0.y); a0[2] = h2f(xc0.z); a0[3] = h2f(xc0.w);
    a1[0] = h2f(xc1.x); a1[1] = h2f(xc1.y); a1[2] = h2f(xc1.z); a1[3] = h2f(xc1.w);
#pragma unroll
    for (int kt = 0; kt < 4; ++kt) {
      a0 = __builtin_amdgcn_mfma_f32_16x16x32_f16(as_f16x8(afr[0][kt]),
                                                  as_f16x8(bfr[kt]), a0, 0, 0, 0);
      a1 = __builtin_amdgcn_mfma_f32_16x16x32_f16(as_f16x8(afr[1][kt]),
                                                  as_f16x8(bfr[kt]), a1, 0, 0, 0);
    }
#pragma unroll
    for (int j = 0; j < 4; ++j) {
      hh[0][j] = tanh_fast(a0[j]);
      hh[1][j] = tanh_fast(a1[j]);
    }
    // pack + write new state: [batch=bl][k = (2w+mi)*16 + g*4 + j]
    uint2 p0 = {h2u(pkrtz(hh[0][0], hh[0][1])), h2u(pkrtz(hh[0][2], hh[0][3]))};
    uint2 p1 = {h2u(pkrtz(hh[1][0], hh[1][1])), h2u(pkrtz(hh[1][2], hh[1][3]))};
    const int w0 = (bl * 256 + (2 * w + 0) * 32 + g * 8) ^ swz;
    const int w1 = (bl * 256 + (2 * w + 1) * 32 + g * 8) ^ swz;
    *(uint2*)((char*)stW + w0) = p0;
    *(uint2*)((char*)stW + w1) = p1;
    __syncthreads();
  };

  // depth-2 prefetch of xw (b64 each). Loads past t=511 land harmlessly
  // inside d_ws (xw is followed by Wih16) — never dereferenced as data.
  ushort4 xA0 = *(const ushort4*)(xb0);
  ushort4 xA1 = *(const ushort4*)(xb1);
  ushort4 xB0 = *(const ushort4*)(xb0 + HIDDEN);
  ushort4 xB1 = *(const ushort4*)(xb1 + HIDDEN);

  for (int t2 = 0; t2 < TSTEPS; t2 += 2) {
    ushort4 c0 = xA0, c1 = xA1;
    xA0 = *(const ushort4*)(xb0 + (size_t)(t2 + 2) * HIDDEN);
    xA1 = *(const ushort4*)(xb1 + (size_t)(t2 + 2) * HIDDEN);
    STEP(t2, &st[0][0][0], &st[1][0][0], c0, c1);  // even t: read st0, write st1

    ushort4 d0 = xB0, d1 = xB1;
    xB0 = *(const ushort4*)(xb0 + (size_t)(t2 + 3) * HIDDEN);
    xB1 = *(const ushort4*)(xb1 + (size_t)(t2 + 3) * HIDDEN);
    STEP(t2 + 1, &st[1][0][0], &st[0][0][0], d0, d1);  // odd t: read st1, write st0
  }

  // fused FC: out[b] = sum_{h'} h_last[b][h'] * W_fc[h'] + b_fc
  const float4 wf0 = *(const float4*)&W_fc[(2 * w + 0) * 16 + g * 4];
  const float4 wf1 = *(const float4*)&W_fc[(2 * w + 1) * 16 + g * 4];
  float partial = hh[0][0] * wf0.x + hh[0][1] * wf0.y + hh[0][2] * wf0.z +
                  hh[0][3] * wf0.w + hh[1][0] * wf1.x + hh[1][1] * wf1.y +
                  hh[1][2] * wf1.z + hh[1][3] * wf1.w;
  red[tid] = partial;
  __syncthreads();
  if (tid < RB) {
    float s = b_fc[0];
#pragma unroll
    for (int q = 0; q < 16; ++q) s += red[q * 16 + tid];
    out[blk * RB + tid] = s;
  }
}

extern "C" void kernel_launch(void* const* d_in, const int* in_sizes, int n_in,
                              void* d_out, int out_size, void* d_ws, size_t ws_size,
                              hipStream_t stream) {
  const float* x    = (const float*)d_in[0];
  const float* W_ih = (const float*)d_in[1];
  const float* W_hh = (const float*)d_in[2];
  const float* b_ih = (const float*)d_in[3];
  const float* b_hh = (const float*)d_in[4];
  const float* W_fc = (const float*)d_in[5];
  const float* b_fc = (const float*)d_in[6];

  char* ws = (char*)d_ws;
  half_t*         xwf16 = (half_t*)ws;                                     // 8 MB
  unsigned short* Wih16 = (unsigned short*)(ws + (8u << 20));              // 512 KB
  unsigned int*   Whh2  = (unsigned int*)(ws + (8u << 20) + (512u << 10)); // 32 KB

  prep_kernel<<<256, 256, 0, stream>>>(W_ih, W_hh, Wih16, Whh2);
  gemm_xw_f16<<<(BATCH * TSTEPS) / GBM, 256, 0, stream>>>(x, Wih16, b_ih, b_hh, xwf16);
  rnn_rec_mfma<<<BATCH / RB, 256, 0, stream>>>(xwf16, Whh2, W_fc, b_fc, (float*)d_out);
}